// Round 20
// baseline (271.373 us; speedup 1.0000x reference)
//
#include <hip/hip_runtime.h>
#include <cstdint>
#include <cstddef>

#define DEVI __device__ __forceinline__

typedef __attribute__((ext_vector_type(8))) short short8;
typedef __attribute__((ext_vector_type(4))) float f32x4;
typedef __attribute__((ext_vector_type(16))) float f32x16;
typedef __attribute__((ext_vector_type(4))) unsigned int u32x4;

static constexpr int Bdim = 2, T = 2048, C = 2048, H = 16, D = 128;
static constexpr int CQ = 3 * C; // 6144

DEVI unsigned short f2bf(float f) {
  unsigned int u = __float_as_uint(f);
  u = (u + 0x7fffu + ((u >> 16) & 1u)) >> 16; // RNE
  return (unsigned short)u;
}
DEVI float bf2f(unsigned int u) { return __uint_as_float(u << 16); }

DEVI unsigned int cvtpk(float lo, float hi) {
  unsigned int r;
  asm("v_cvt_pk_bf16_f32 %0, %1, %2" : "=v"(r) : "v"(lo), "v"(hi));
  return r;
}

DEVI void gload_lds16(const void* g, void* l) {
  __builtin_amdgcn_global_load_lds((const __attribute__((address_space(1))) void*)g,
                                   (__attribute__((address_space(3))) void*)l, 16, 0, 0);
}

// ---------------- merged f32 -> bf16 converts (x, wqkv, wo in one launch) ----------------
__global__ __launch_bounds__(256) void convert_all(const float* __restrict__ x,
                                                   const float* __restrict__ wqkv,
                                                   const float* __restrict__ wo,
                                                   unsigned short* __restrict__ xb,
                                                   unsigned short* __restrict__ wqkvb,
                                                   unsigned short* __restrict__ wob) {
  int bid = blockIdx.x;
  const float* src;
  unsigned short* dst;
  if (bid < 8192) {
    src = x; dst = xb;
  } else if (bid < 8192 + 12288) {
    bid -= 8192; src = wqkv; dst = wqkvb;
  } else {
    bid -= 8192 + 12288; src = wo; dst = wob;
  }
  const int i = (bid * 256 + threadIdx.x) * 4;
  float4 v = *(const float4*)&src[i];
  uint2 o;
  o.x = (unsigned)f2bf(v.x) | ((unsigned)f2bf(v.y) << 16);
  o.y = (unsigned)f2bf(v.z) | ((unsigned)f2bf(v.w) << 16);
  *(uint2*)&dst[i] = o;
}

// ---------------- bf16 GEMM, B^T input: out[m][n] = sum_k A[m][k]*Bm[n][k] ----------------
// r7 fragment geometry (16x16x32, chunk-XOR swizzle both sides, conflict-free)
// + r12 single-barrier double-buffer schedule: one vmcnt(0)+barrier per K-step
// at loop top (waits on loads issued a full compute-phase earlier), then issue
// stage(t+1)->buf^1, then compute(t). 64 KB LDS, 2 blocks/CU.
template <int OUT_BF16>
__global__ __launch_bounds__(256) void gemm_bt(const unsigned short* __restrict__ A,
                                               const unsigned short* __restrict__ Bm,
                                               void* __restrict__ outp,
                                               int M, int N, int Kd) {
  __shared__ __align__(16) unsigned short lds_a[2][128 * 64];
  __shared__ __align__(16) unsigned short lds_b[2][128 * 64];
  const int tid = threadIdx.x;
  const int wid = tid >> 6, lane = tid & 63;
  const int lg = lane >> 4, lc = lane & 15;
  const int m0 = blockIdx.y * 128, n0 = blockIdx.x * 128;
  const int wr = (wid >> 1) * 64, wc = (wid & 1) * 64;
  const int srow = wid * 8 + (lane >> 3);
  const int schunk = lane & 7;

  f32x4 acc[4][4] = {};

  // ---- prologue: stage K-tile 0 into buf 0 ----
#pragma unroll
  for (int j = 0; j < 4; ++j) {
    const int row = j * 32 + srow;
    const int cc = schunk ^ (row & 7);
    gload_lds16(&A[(size_t)(m0 + row) * Kd + cc * 8], &lds_a[0][j * 2048 + wid * 512]);
    gload_lds16(&Bm[(size_t)(n0 + row) * Kd + cc * 8], &lds_b[0][j * 2048 + wid * 512]);
  }

  int cur = 0;
  for (int k0 = 0; k0 < Kd; k0 += 64) {
    // my stage(k0 -> cur) landed; all waves done reading buf cur^1
    asm volatile("s_waitcnt vmcnt(0)" ::: "memory");
    __builtin_amdgcn_s_barrier();
    __builtin_amdgcn_sched_barrier(0);

    // ---- issue stage(k0+64 -> cur^1) (lands during compute below) ----
    if (k0 + 64 < Kd) {
#pragma unroll
      for (int j = 0; j < 4; ++j) {
        const int row = j * 32 + srow;
        const int cc = schunk ^ (row & 7);
        gload_lds16(&A[(size_t)(m0 + row) * Kd + k0 + 64 + cc * 8],
                    &lds_a[cur ^ 1][j * 2048 + wid * 512]);
        gload_lds16(&Bm[(size_t)(n0 + row) * Kd + k0 + 64 + cc * 8],
                    &lds_b[cur ^ 1][j * 2048 + wid * 512]);
      }
    }
    __builtin_amdgcn_sched_barrier(0);

    // ---- compute K-tile from buf cur (16x16 frags, conflict-free) ----
    __builtin_amdgcn_s_setprio(1);
#pragma unroll
    for (int kk = 0; kk < 2; ++kk) {
      short8 af[4], bf[4];
#pragma unroll
      for (int m = 0; m < 4; ++m) {
        const int row = wr + m * 16 + lc;
        af[m] = *(const short8*)&lds_a[cur][row * 64 + (((kk * 4 + lg) ^ (row & 7)) * 8)];
      }
#pragma unroll
      for (int n = 0; n < 4; ++n) {
        const int row = wc + n * 16 + lc;
        bf[n] = *(const short8*)&lds_b[cur][row * 64 + (((kk * 4 + lg) ^ (row & 7)) * 8)];
      }
#pragma unroll
      for (int m = 0; m < 4; ++m)
#pragma unroll
        for (int n = 0; n < 4; ++n)
          acc[m][n] = __builtin_amdgcn_mfma_f32_16x16x32_bf16(af[m], bf[n], acc[m][n], 0, 0, 0);
    }
    __builtin_amdgcn_s_setprio(0);
    cur ^= 1;
  }

#pragma unroll
  for (int m = 0; m < 4; ++m)
#pragma unroll
    for (int n = 0; n < 4; ++n)
#pragma unroll
      for (int r = 0; r < 4; ++r) {
        const int row = m0 + wr + m * 16 + lg * 4 + r;
        const int col = n0 + wc + n * 16 + lc;
        const float v = acc[m][n][r];
        if (OUT_BF16)
          ((unsigned short*)outp)[(size_t)row * N + col] = f2bf(v);
        else
          ((float*)outp)[(size_t)row * N + col] = v;
      }
}

// ---------------- merged RoPE + V-transpose (one launch) ----------------
__global__ __launch_bounds__(256) void rope_vt_kernel(const unsigned short* __restrict__ qkv,
                                                      const float* __restrict__ cosb,
                                                      const float* __restrict__ sinb,
                                                      unsigned short* __restrict__ Qr,
                                                      unsigned short* __restrict__ Kr,
                                                      unsigned short* __restrict__ Vt) {
  if (blockIdx.x < 16384) {
    const int idx = blockIdx.x * 256 + threadIdx.x;
    const int i = idx & 63;
    const int h = (idx >> 6) & (H - 1);
    const int tg = idx >> 10;
    const int t = tg & (T - 1);
    const int b = tg >> 11;
    const float c = cosb[t * 64 + i], s = sinb[t * 64 + i];
    const unsigned short* row = qkv + (size_t)tg * CQ;
    const unsigned int q = *(const unsigned int*)&row[h * D + 2 * i];
    const unsigned int k = *(const unsigned int*)&row[C + h * D + 2 * i];
    const float q0 = bf2f(q & 0xffffu), q1 = bf2f(q >> 16);
    const float k0 = bf2f(k & 0xffffu), k1 = bf2f(k >> 16);
    const float SC = 0.08838834764831845f * 1.4426950408889634f; // 1/sqrt(128)*log2(e)
    const float q0r = (q0 * c - q1 * s) * SC, q1r = (q0 * s + q1 * c) * SC;
    const float k0r = k0 * c - k1 * s, k1r = k0 * s + k1 * c;
    const size_t off = ((size_t)(b * H + h) * T + t) * D + 2 * i;
    *(unsigned int*)&Qr[off] = (unsigned)f2bf(q0r) | ((unsigned)f2bf(q1r) << 16);
    *(unsigned int*)&Kr[off] = (unsigned)f2bf(k0r) | ((unsigned)f2bf(k1r) << 16);
  } else {
    __shared__ unsigned short tile[64][65];
    const int bid2 = blockIdx.x - 16384;
    const int t0 = (bid2 & 31) * 64;
    const int d0 = ((bid2 >> 5) & 1) * 64;
    const int bh = bid2 >> 6, b = bh >> 4, h = bh & (H - 1);
    const int tx = threadIdx.x & 63, ty = threadIdx.x >> 6;
#pragma unroll
    for (int rr = 0; rr < 64; rr += 4)
      tile[rr + ty][tx] = qkv[(size_t)(b * T + t0 + rr + ty) * CQ + 2 * C + h * D + d0 + tx];
    __syncthreads();
#pragma unroll
    for (int rr = 0; rr < 64; rr += 4)
      Vt[((size_t)bh * D + d0 + rr + ty) * T + t0 + tx] = tile[tx][rr + ty];
  }
}

// ---------------- causal flash attention: swapped-operand 32x32 MFMA + T14 reg-staging ----------------
// r10 schedule, KV-SPLIT-2 (r19, proven): 1024 blocks = 32 bh x 16 qt x 2 halves.
__global__ __launch_bounds__(256, 2) void flash_attn(const unsigned short* __restrict__ Q,
                                                     const unsigned short* __restrict__ K,
                                                     const unsigned short* __restrict__ Vt,
                                                     unsigned short* __restrict__ OA,
                                                     unsigned short* __restrict__ OB,
                                                     float2* __restrict__ ml) {
  __shared__ __align__(16) unsigned short ldsK[64 * 128];  // 16 KB, [kv 64][256B] swizzled
  __shared__ __align__(16) unsigned short ldsV[64 * 128];  // 16 KB

  const int bid = blockIdx.x;
  const int lid = (bid & 7) * 128 + (bid >> 3);  // bijective XCD-chunk swizzle (1024)
  const int bh = lid >> 5;                       // 4 heads per XCD chunk
  const int qt = 15 - ((lid >> 1) & 15);         // heavy blocks first
  const int hf = lid & 1;                        // kv half
  const int wid = threadIdx.x >> 6;
  const int lane = threadIdx.x & 63;
  const int l31 = lane & 31, l15 = lane & 15;
  const int hi = lane >> 5;
  const int b = bh >> 4, h = bh & (H - 1);
  const int q0w = qt * 128 + wid * 32;
  const int qrow = q0w + l31;

  const unsigned short* Qh = Q + (size_t)bh * T * D;
  const unsigned short* Kh = K + (size_t)bh * T * D;
  const unsigned short* Vh = Vt + (size_t)bh * D * T;

  const int sr = lane >> 4;  // staging row-in-group 0..3
  const int tstart = hf ? (qt + 1) : 0;
  const int tend = hf ? (2 * qt + 2) : (qt + 1);

  short8 qf[8];
#pragma unroll
  for (int ds = 0; ds < 8; ++ds)
    qf[ds] = *(const short8*)&Qh[(size_t)qrow * D + ds * 16 + hi * 8];

  f32x16 oacc[4] = {};
  float m_run = -1e30f, l_run = 0.f;

  u32x4 rK[4], rV[4];

  // ---- prologue: load tile tstart into regs ----
#pragma unroll
  for (int j = 0; j < 4; ++j) {
    const int r0 = (wid * 4 + j) * 4;
    const int row = r0 + sr;
    const int cc = l15 ^ (row & 15);
    rK[j] = *(const u32x4*)&Kh[(size_t)(tstart * 64 + row) * D + cc * 8];
    const int d = row + ((cc >> 3) << 6);
    rV[j] = *(const u32x4*)&Vh[(size_t)d * T + tstart * 64 + (cc & 7) * 8];
  }

  for (int t = tstart; t < tend; ++t) {
    const int kv0 = t * 64;

    // ---- barrier 1: all waves done reading LDS tile t-1 ----
    __builtin_amdgcn_s_barrier();

    // ---- write tile t from regs (compiler inserts counted vmcnt) ----
#pragma unroll
    for (int j = 0; j < 4; ++j) {
      const int r0 = (wid * 4 + j) * 4;
      *(u32x4*)((char*)ldsK + r0 * 256 + lane * 16) = rK[j];
      *(u32x4*)((char*)ldsV + r0 * 256 + lane * 16) = rV[j];
    }
    asm volatile("s_waitcnt lgkmcnt(0)" ::: "memory");
    __builtin_amdgcn_s_barrier();
    __builtin_amdgcn_sched_barrier(0);

    // ---- issue tile t+1 loads -> regs (in flight through compute) ----
    if (t + 1 < tend) {
      const int kvn = kv0 + 64;
#pragma unroll
      for (int j = 0; j < 4; ++j) {
        const int r0 = (wid * 4 + j) * 4;
        const int row = r0 + sr;
        const int cc = l15 ^ (row & 15);
        rK[j] = *(const u32x4*)&Kh[(size_t)(kvn + row) * D + cc * 8];
        const int d = row + ((cc >> 3) << 6);
        rV[j] = *(const u32x4*)&Vh[(size_t)d * T + kvn + (cc & 7) * 8];
      }
    }
    __builtin_amdgcn_sched_barrier(0);

    if (kv0 <= q0w + 31) {
      // ---- QK^T: S^T[kv][q]; lane owns q-col ----
      f32x16 s0 = {}, s1 = {};
      __builtin_amdgcn_s_setprio(1);
#pragma unroll
      for (int ds = 0; ds < 8; ++ds) {
        const int cs = ((ds * 2 + hi) ^ l15) * 8;
        const short8 k0 = *(const short8*)&ldsK[l31 * 128 + cs];
        const short8 k1 = *(const short8*)&ldsK[(32 + l31) * 128 + cs];
        s0 = __builtin_amdgcn_mfma_f32_32x32x16_bf16(k0, qf[ds], s0, 0, 0, 0);
        s1 = __builtin_amdgcn_mfma_f32_32x32x16_bf16(k1, qf[ds], s1, 0, 0, 0);
      }
      __builtin_amdgcn_s_setprio(0);

      // ---- mask (any tile reaching past the wave's FIRST q row) ----
      if (kv0 + 63 > q0w) {
#pragma unroll
        for (int r = 0; r < 16; ++r) {
          const int kvr = kv0 + (r & 3) + 8 * (r >> 2) + 4 * hi;
          s0[r] = (kvr <= qrow) ? s0[r] : -1e30f;
          s1[r] = (kvr + 32 <= qrow) ? s1[r] : -1e30f;
        }
      }

      // ---- in-register softmax (per-lane scalar m/l) ----
      float mt[8];
#pragma unroll
      for (int r = 0; r < 8; ++r)
        mt[r] = fmaxf(fmaxf(s0[r], s0[r + 8]), fmaxf(s1[r], s1[r + 8]));
#pragma unroll
      for (int r = 0; r < 4; ++r) mt[r] = fmaxf(mt[r], mt[r + 4]);
      float mx = fmaxf(fmaxf(mt[0], mt[1]), fmaxf(mt[2], mt[3]));
      mx = fmaxf(mx, __shfl_xor(mx, 32));
      const float mnew = fmaxf(m_run, mx);
      if (__any(mnew > m_run)) {  // exact skip: f==1 when max unchanged
        const float f = exp2f(m_run - mnew);
        m_run = mnew;
        l_run *= f;
#pragma unroll
        for (int blk = 0; blk < 4; ++blk) oacc[blk] *= f;
      }
#pragma unroll
      for (int r = 0; r < 16; ++r) {
        s0[r] = exp2f(s0[r] - m_run);
        s1[r] = exp2f(s1[r] - m_run);
      }
      {
        float a0 = 0.f, a1 = 0.f, a2 = 0.f, a3 = 0.f;
#pragma unroll
        for (int r = 0; r < 16; r += 4) {
          a0 += s0[r] + s1[r];
          a1 += s0[r + 1] + s1[r + 1];
          a2 += s0[r + 2] + s1[r + 2];
          a3 += s0[r + 3] + s1[r + 3];
        }
        l_run += (a0 + a1) + (a2 + a3);
      }

      // ---- PV: O^T += V^T * P^T, P redistributed in-register ----
      __builtin_amdgcn_s_setprio(1);
#pragma unroll
      for (int ks = 0; ks < 4; ++ks) {
        const int rb = (ks & 1) * 8;
        const f32x16& S = (ks < 2) ? s0 : s1;
        const unsigned int w0 = cvtpk(S[rb + 0], S[rb + 1]);
        const unsigned int w1 = cvtpk(S[rb + 2], S[rb + 3]);
        const unsigned int w2 = cvtpk(S[rb + 4], S[rb + 5]);
        const unsigned int w3 = cvtpk(S[rb + 6], S[rb + 7]);
        const unsigned int x0 = (unsigned int)__shfl_xor((int)w0, 32);
        const unsigned int x1 = (unsigned int)__shfl_xor((int)w1, 32);
        const unsigned int x2 = (unsigned int)__shfl_xor((int)w2, 32);
        const unsigned int x3 = (unsigned int)__shfl_xor((int)w3, 32);
        u32x4 av;
        av[0] = hi ? x2 : w0;
        av[1] = hi ? x3 : w1;
        av[2] = hi ? w2 : x0;
        av[3] = hi ? w3 : x1;
        const short8 pf = __builtin_bit_cast(short8, av);
#pragma unroll
        for (int blk = 0; blk < 4; ++blk) {
          const int row2 = (blk & 1) * 32 + l31;
          const int cs = ((((blk >> 1) * 8) + ks * 2 + hi) ^ l15) * 8;
          const short8 vf = *(const short8*)&ldsV[row2 * 128 + cs];
          oacc[blk] = __builtin_amdgcn_mfma_f32_32x32x16_bf16(vf, pf, oacc[blk], 0, 0, 0);
        }
      }
      __builtin_amdgcn_s_setprio(0);
    }
  }

  // ---- epilogue: pair-reduce l, own-l normalize, store O partial + (m,l) ----
  const float l = l_run + __shfl_xor(l_run, 32);
  const float inv = (l > 0.f) ? (1.0f / l) : 0.f;
  unsigned short* yrow = (hf ? OB : OA) + ((size_t)(b * T + qrow)) * C + h * D;
#pragma unroll
  for (int blk = 0; blk < 4; ++blk)
#pragma unroll
    for (int g = 0; g < 4; ++g) {
      const int d0 = blk * 32 + 8 * g + 4 * hi;
      uint2 st;
      st.x = cvtpk(oacc[blk][4 * g + 0] * inv, oacc[blk][4 * g + 1] * inv);
      st.y = cvtpk(oacc[blk][4 * g + 2] * inv, oacc[blk][4 * g + 3] * inv);
      *(uint2*)&yrow[d0] = st;
    }
  if (hi == 0) {
    float2 v;
    v.x = m_run;
    v.y = l;
    ml[(size_t)hf * (Bdim * H * T) + (size_t)bh * T + qrow] = v;
  }
}

// ---------------- combine the two kv-half partials ----------------
__global__ __launch_bounds__(256) void combine_halves(const unsigned short* __restrict__ OA,
                                                      const unsigned short* __restrict__ OB,
                                                      const float2* __restrict__ ml,
                                                      unsigned short* __restrict__ Y) {
  const int i = blockIdx.x * 256 + threadIdx.x;  // [0, B*H*T*16)
  const int d0 = (i & 15) * 8;
  const int rowid = i >> 4;                      // bh*T + t
  const int bh = rowid >> 11, t = rowid & (T - 1);
  const int b = bh >> 4, h = bh & (H - 1);
  const float2 a = ml[rowid];
  const float2 bb = ml[(size_t)(Bdim * H * T) + rowid];
  const float m = fmaxf(a.x, bb.x);
  const float wA = a.y * exp2f(a.x - m);
  const float wB = bb.y * exp2f(bb.x - m);
  const float den = wA + wB;  // > 0: half A always has >=1 unmasked key
  const float fA = wA / den, fB = wB / den;
  const size_t off = ((size_t)(b * T + t)) * C + h * D + d0;
  const u32x4 ra = *(const u32x4*)&OA[off];
  const u32x4 rb = *(const u32x4*)&OB[off];
  u32x4 w;
#pragma unroll
  for (int e = 0; e < 4; ++e) {
    const float o0 = bf2f(ra[e] & 0xffffu) * fA + bf2f(rb[e] & 0xffffu) * fB;
    const float o1 = bf2f(ra[e] >> 16) * fA + bf2f(rb[e] >> 16) * fB;
    w[e] = cvtpk(o0, o1);
  }
  *(u32x4*)&Y[off] = w;
}

// ---------------- launch ----------------
extern "C" void kernel_launch(void* const* d_in, const int* in_sizes, int n_in,
                              void* d_out, int out_size, void* d_ws, size_t ws_size,
                              hipStream_t stream) {
  const float* x = (const float*)d_in[0];
  const float* wqkv = (const float*)d_in[1];
  const float* wo = (const float*)d_in[2];
  const float* rc = (const float*)d_in[3];
  const float* rs = (const float*)d_in[4];
  float* out = (float*)d_out;
  char* ws = (char*)d_ws;

  unsigned short* xb    = (unsigned short*)(ws + 0);           // 16.8 MB
  unsigned short* wqkvb = (unsigned short*)(ws + 16777216);    // 25.2 MB
  unsigned short* qkv   = (unsigned short*)(ws + 41943040);    // 50.3 MB
  unsigned short* Qr    = (unsigned short*)(ws + 92274688);    // 16.8 MB
  unsigned short* Kr    = (unsigned short*)(ws + 109051904);   // 16.8 MB
  unsigned short* wob   = (unsigned short*)(ws + 125829120);   // 8.4 MB
  unsigned short* Vt  = xb;    // alias: xb dead after GEMM1
  // flash-phase aliases inside the (then-dead) qkv slot:
  unsigned short* OA  = (unsigned short*)(ws + 41943040);      // 16.8 MB
  unsigned short* OB  = (unsigned short*)(ws + 58720256);      // 16.8 MB
  float2*         ml  = (float2*)(ws + 75497472);              // 1.0 MB
  unsigned short* Yf  = Qr;    // alias: Qr dead after flash

  convert_all<<<8192 + 12288 + 4096, 256, 0, stream>>>(x, wqkv, wo, xb, wqkvb, wob);
  gemm_bt<1><<<dim3(CQ / 128, (Bdim * T) / 128), 256, 0, stream>>>(xb, wqkvb, (void*)qkv,
                                                                   Bdim * T, CQ, C);
  rope_vt_kernel<<<18432, 256, 0, stream>>>(qkv, rc, rs, Qr, Kr, Vt);
  flash_attn<<<1024, 256, 0, stream>>>(Qr, Kr, Vt, OA, OB, ml);
  combine_halves<<<4096, 256, 0, stream>>>(OA, OB, ml, Yf);
  gemm_bt<0><<<dim3(C / 128, (Bdim * T) / 128), 256, 0, stream>>>(Yf, wob, (void*)out,
                                                                  Bdim * T, C, C);
}

// Round 21
// 262.009 us; speedup vs baseline: 1.0357x; 1.0357x over previous
//
#include <hip/hip_runtime.h>
#include <cstdint>
#include <cstddef>

#define DEVI __device__ __forceinline__

typedef __attribute__((ext_vector_type(8))) short short8;
typedef __attribute__((ext_vector_type(4))) float f32x4;
typedef __attribute__((ext_vector_type(16))) float f32x16;
typedef __attribute__((ext_vector_type(4))) unsigned int u32x4;

static constexpr int Bdim = 2, T = 2048, C = 2048, H = 16, D = 128;
static constexpr int CQ = 3 * C; // 6144

DEVI unsigned short f2bf(float f) {
  unsigned int u = __float_as_uint(f);
  u = (u + 0x7fffu + ((u >> 16) & 1u)) >> 16; // RNE
  return (unsigned short)u;
}
DEVI float bf2f(unsigned int u) { return __uint_as_float(u << 16); }

DEVI unsigned int cvtpk(float lo, float hi) {
  unsigned int r;
  asm("v_cvt_pk_bf16_f32 %0, %1, %2" : "=v"(r) : "v"(lo), "v"(hi));
  return r;
}

DEVI void gload_lds16(const void* g, void* l) {
  __builtin_amdgcn_global_load_lds((const __attribute__((address_space(1))) void*)g,
                                   (__attribute__((address_space(3))) void*)l, 16, 0, 0);
}

// ---------------- merged f32 -> bf16 converts (x, wqkv, wo in one launch) ----------------
__global__ __launch_bounds__(256) void convert_all(const float* __restrict__ x,
                                                   const float* __restrict__ wqkv,
                                                   const float* __restrict__ wo,
                                                   unsigned short* __restrict__ xb,
                                                   unsigned short* __restrict__ wqkvb,
                                                   unsigned short* __restrict__ wob) {
  int bid = blockIdx.x;
  const float* src;
  unsigned short* dst;
  if (bid < 8192) {
    src = x; dst = xb;
  } else if (bid < 8192 + 12288) {
    bid -= 8192; src = wqkv; dst = wqkvb;
  } else {
    bid -= 8192 + 12288; src = wo; dst = wob;
  }
  const int i = (bid * 256 + threadIdx.x) * 4;
  float4 v = *(const float4*)&src[i];
  uint2 o;
  o.x = (unsigned)f2bf(v.x) | ((unsigned)f2bf(v.y) << 16);
  o.y = (unsigned)f2bf(v.z) | ((unsigned)f2bf(v.w) << 16);
  *(uint2*)&dst[i] = o;
}

// ---------------- bf16 GEMM, B^T input (r7-exact, proven 963 TF) ----------------
template <int OUT_BF16>
__global__ __launch_bounds__(256) void gemm_bt(const unsigned short* __restrict__ A,
                                               const unsigned short* __restrict__ Bm,
                                               void* __restrict__ outp,
                                               int M, int N, int Kd) {
  __shared__ __align__(16) unsigned short lds_a[128 * 64];
  __shared__ __align__(16) unsigned short lds_b[128 * 64];
  const int tid = threadIdx.x;
  const int wid = tid >> 6, lane = tid & 63;
  const int lg = lane >> 4, lc = lane & 15;
  const int m0 = blockIdx.y * 128, n0 = blockIdx.x * 128;
  const int wr = (wid >> 1) * 64, wc = (wid & 1) * 64;
  const int srow = wid * 8 + (lane >> 3);
  const int schunk = lane & 7;

  f32x4 acc[4][4] = {};

  for (int k0 = 0; k0 < Kd; k0 += 64) {
    __syncthreads();
#pragma unroll
    for (int j = 0; j < 4; ++j) {
      const int row = j * 32 + srow;
      const int cc = schunk ^ (row & 7);
      gload_lds16(&A[(size_t)(m0 + row) * Kd + k0 + cc * 8], &lds_a[j * 2048 + wid * 512]);
      gload_lds16(&Bm[(size_t)(n0 + row) * Kd + k0 + cc * 8], &lds_b[j * 2048 + wid * 512]);
    }
    __syncthreads();
    __builtin_amdgcn_s_setprio(1);
#pragma unroll
    for (int kk = 0; kk < 2; ++kk) {
      short8 af[4], bf[4];
#pragma unroll
      for (int m = 0; m < 4; ++m) {
        const int row = wr + m * 16 + lc;
        af[m] = *(const short8*)&lds_a[row * 64 + (((kk * 4 + lg) ^ (row & 7)) * 8)];
      }
#pragma unroll
      for (int n = 0; n < 4; ++n) {
        const int row = wc + n * 16 + lc;
        bf[n] = *(const short8*)&lds_b[row * 64 + (((kk * 4 + lg) ^ (row & 7)) * 8)];
      }
#pragma unroll
      for (int m = 0; m < 4; ++m)
#pragma unroll
        for (int n = 0; n < 4; ++n)
          acc[m][n] = __builtin_amdgcn_mfma_f32_16x16x32_bf16(af[m], bf[n], acc[m][n], 0, 0, 0);
    }
    __builtin_amdgcn_s_setprio(0);
  }

#pragma unroll
  for (int m = 0; m < 4; ++m)
#pragma unroll
    for (int n = 0; n < 4; ++n)
#pragma unroll
      for (int r = 0; r < 4; ++r) {
        const int row = m0 + wr + m * 16 + lg * 4 + r;
        const int col = n0 + wc + n * 16 + lc;
        const float v = acc[m][n][r];
        if (OUT_BF16)
          ((unsigned short*)outp)[(size_t)row * N + col] = f2bf(v);
        else
          ((float*)outp)[(size_t)row * N + col] = v;
      }
}

// ---------------- merged RoPE + V-transpose (one launch) ----------------
__global__ __launch_bounds__(256) void rope_vt_kernel(const unsigned short* __restrict__ qkv,
                                                      const float* __restrict__ cosb,
                                                      const float* __restrict__ sinb,
                                                      unsigned short* __restrict__ Qr,
                                                      unsigned short* __restrict__ Kr,
                                                      unsigned short* __restrict__ Vt) {
  if (blockIdx.x < 16384) {
    const int idx = blockIdx.x * 256 + threadIdx.x;
    const int i = idx & 63;
    const int h = (idx >> 6) & (H - 1);
    const int tg = idx >> 10;
    const int t = tg & (T - 1);
    const int b = tg >> 11;
    const float c = cosb[t * 64 + i], s = sinb[t * 64 + i];
    const unsigned short* row = qkv + (size_t)tg * CQ;
    const unsigned int q = *(const unsigned int*)&row[h * D + 2 * i];
    const unsigned int k = *(const unsigned int*)&row[C + h * D + 2 * i];
    const float q0 = bf2f(q & 0xffffu), q1 = bf2f(q >> 16);
    const float k0 = bf2f(k & 0xffffu), k1 = bf2f(k >> 16);
    const float SC = 0.08838834764831845f * 1.4426950408889634f; // 1/sqrt(128)*log2(e)
    const float q0r = (q0 * c - q1 * s) * SC, q1r = (q0 * s + q1 * c) * SC;
    const float k0r = k0 * c - k1 * s, k1r = k0 * s + k1 * c;
    const size_t off = ((size_t)(b * H + h) * T + t) * D + 2 * i;
    *(unsigned int*)&Qr[off] = (unsigned)f2bf(q0r) | ((unsigned)f2bf(q1r) << 16);
    *(unsigned int*)&Kr[off] = (unsigned)f2bf(k0r) | ((unsigned)f2bf(k1r) << 16);
  } else {
    __shared__ unsigned short tile[64][65];
    const int bid2 = blockIdx.x - 16384;
    const int t0 = (bid2 & 31) * 64;
    const int d0 = ((bid2 >> 5) & 1) * 64;
    const int bh = bid2 >> 6, b = bh >> 4, h = bh & (H - 1);
    const int tx = threadIdx.x & 63, ty = threadIdx.x >> 6;
#pragma unroll
    for (int rr = 0; rr < 64; rr += 4)
      tile[rr + ty][tx] = qkv[(size_t)(b * T + t0 + rr + ty) * CQ + 2 * C + h * D + d0 + tx];
    __syncthreads();
#pragma unroll
    for (int rr = 0; rr < 64; rr += 4)
      Vt[((size_t)bh * D + d0 + rr + ty) * T + t0 + tx] = tile[tx][rr + ty];
  }
}

// ---------------- causal flash attention: swapped-operand 32x32 MFMA + T14 reg-staging ----------------
// r10 schedule, KV-SPLIT-2 (r19, proven): 1024 blocks = 32 bh x 16 qt x 2 halves.
__global__ __launch_bounds__(256, 2) void flash_attn(const unsigned short* __restrict__ Q,
                                                     const unsigned short* __restrict__ K,
                                                     const unsigned short* __restrict__ Vt,
                                                     unsigned short* __restrict__ OA,
                                                     unsigned short* __restrict__ OB,
                                                     float2* __restrict__ ml) {
  __shared__ __align__(16) unsigned short ldsK[64 * 128];  // 16 KB, [kv 64][256B] swizzled
  __shared__ __align__(16) unsigned short ldsV[64 * 128];  // 16 KB

  const int bid = blockIdx.x;
  const int lid = (bid & 7) * 128 + (bid >> 3);  // bijective XCD-chunk swizzle (1024)
  const int bh = lid >> 5;                       // 4 heads per XCD chunk
  const int qt = 15 - ((lid >> 1) & 15);         // heavy blocks first
  const int hf = lid & 1;                        // kv half
  const int wid = threadIdx.x >> 6;
  const int lane = threadIdx.x & 63;
  const int l31 = lane & 31, l15 = lane & 15;
  const int hi = lane >> 5;
  const int b = bh >> 4, h = bh & (H - 1);
  const int q0w = qt * 128 + wid * 32;
  const int qrow = q0w + l31;

  const unsigned short* Qh = Q + (size_t)bh * T * D;
  const unsigned short* Kh = K + (size_t)bh * T * D;
  const unsigned short* Vh = Vt + (size_t)bh * D * T;

  const int sr = lane >> 4;  // staging row-in-group 0..3
  const int tstart = hf ? (qt + 1) : 0;
  const int tend = hf ? (2 * qt + 2) : (qt + 1);

  short8 qf[8];
#pragma unroll
  for (int ds = 0; ds < 8; ++ds)
    qf[ds] = *(const short8*)&Qh[(size_t)qrow * D + ds * 16 + hi * 8];

  f32x16 oacc[4] = {};
  float m_run = -1e30f, l_run = 0.f;

  u32x4 rK[4], rV[4];

  // ---- prologue: load tile tstart into regs ----
#pragma unroll
  for (int j = 0; j < 4; ++j) {
    const int r0 = (wid * 4 + j) * 4;
    const int row = r0 + sr;
    const int cc = l15 ^ (row & 15);
    rK[j] = *(const u32x4*)&Kh[(size_t)(tstart * 64 + row) * D + cc * 8];
    const int d = row + ((cc >> 3) << 6);
    rV[j] = *(const u32x4*)&Vh[(size_t)d * T + tstart * 64 + (cc & 7) * 8];
  }

  for (int t = tstart; t < tend; ++t) {
    const int kv0 = t * 64;

    // ---- barrier 1: all waves done reading LDS tile t-1 ----
    __builtin_amdgcn_s_barrier();

    // ---- write tile t from regs (compiler inserts counted vmcnt) ----
#pragma unroll
    for (int j = 0; j < 4; ++j) {
      const int r0 = (wid * 4 + j) * 4;
      *(u32x4*)((char*)ldsK + r0 * 256 + lane * 16) = rK[j];
      *(u32x4*)((char*)ldsV + r0 * 256 + lane * 16) = rV[j];
    }
    asm volatile("s_waitcnt lgkmcnt(0)" ::: "memory");
    __builtin_amdgcn_s_barrier();
    __builtin_amdgcn_sched_barrier(0);

    // ---- issue tile t+1 loads -> regs (in flight through compute) ----
    if (t + 1 < tend) {
      const int kvn = kv0 + 64;
#pragma unroll
      for (int j = 0; j < 4; ++j) {
        const int r0 = (wid * 4 + j) * 4;
        const int row = r0 + sr;
        const int cc = l15 ^ (row & 15);
        rK[j] = *(const u32x4*)&Kh[(size_t)(kvn + row) * D + cc * 8];
        const int d = row + ((cc >> 3) << 6);
        rV[j] = *(const u32x4*)&Vh[(size_t)d * T + kvn + (cc & 7) * 8];
      }
    }
    __builtin_amdgcn_sched_barrier(0);

    if (kv0 <= q0w + 31) {
      // ---- QK^T: S^T[kv][q]; lane owns q-col ----
      f32x16 s0 = {}, s1 = {};
      __builtin_amdgcn_s_setprio(1);
#pragma unroll
      for (int ds = 0; ds < 8; ++ds) {
        const int cs = ((ds * 2 + hi) ^ l15) * 8;
        const short8 k0 = *(const short8*)&ldsK[l31 * 128 + cs];
        const short8 k1 = *(const short8*)&ldsK[(32 + l31) * 128 + cs];
        s0 = __builtin_amdgcn_mfma_f32_32x32x16_bf16(k0, qf[ds], s0, 0, 0, 0);
        s1 = __builtin_amdgcn_mfma_f32_32x32x16_bf16(k1, qf[ds], s1, 0, 0, 0);
      }
      __builtin_amdgcn_s_setprio(0);

      // ---- mask (any tile reaching past the wave's FIRST q row) ----
      if (kv0 + 63 > q0w) {
#pragma unroll
        for (int r = 0; r < 16; ++r) {
          const int kvr = kv0 + (r & 3) + 8 * (r >> 2) + 4 * hi;
          s0[r] = (kvr <= qrow) ? s0[r] : -1e30f;
          s1[r] = (kvr + 32 <= qrow) ? s1[r] : -1e30f;
        }
      }

      // ---- in-register softmax (per-lane scalar m/l) ----
      float mt[8];
#pragma unroll
      for (int r = 0; r < 8; ++r)
        mt[r] = fmaxf(fmaxf(s0[r], s0[r + 8]), fmaxf(s1[r], s1[r + 8]));
#pragma unroll
      for (int r = 0; r < 4; ++r) mt[r] = fmaxf(mt[r], mt[r + 4]);
      float mx = fmaxf(fmaxf(mt[0], mt[1]), fmaxf(mt[2], mt[3]));
      mx = fmaxf(mx, __shfl_xor(mx, 32));
      const float mnew = fmaxf(m_run, mx);
      if (__any(mnew > m_run)) {  // exact skip: f==1 when max unchanged
        const float f = exp2f(m_run - mnew);
        m_run = mnew;
        l_run *= f;
#pragma unroll
        for (int blk = 0; blk < 4; ++blk) oacc[blk] *= f;
      }
#pragma unroll
      for (int r = 0; r < 16; ++r) {
        s0[r] = exp2f(s0[r] - m_run);
        s1[r] = exp2f(s1[r] - m_run);
      }
      {
        float a0 = 0.f, a1 = 0.f, a2 = 0.f, a3 = 0.f;
#pragma unroll
        for (int r = 0; r < 16; r += 4) {
          a0 += s0[r] + s1[r];
          a1 += s0[r + 1] + s1[r + 1];
          a2 += s0[r + 2] + s1[r + 2];
          a3 += s0[r + 3] + s1[r + 3];
        }
        l_run += (a0 + a1) + (a2 + a3);
      }

      // ---- PV: O^T += V^T * P^T, P redistributed in-register ----
      __builtin_amdgcn_s_setprio(1);
#pragma unroll
      for (int ks = 0; ks < 4; ++ks) {
        const int rb = (ks & 1) * 8;
        const f32x16& S = (ks < 2) ? s0 : s1;
        const unsigned int w0 = cvtpk(S[rb + 0], S[rb + 1]);
        const unsigned int w1 = cvtpk(S[rb + 2], S[rb + 3]);
        const unsigned int w2 = cvtpk(S[rb + 4], S[rb + 5]);
        const unsigned int w3 = cvtpk(S[rb + 6], S[rb + 7]);
        const unsigned int x0 = (unsigned int)__shfl_xor((int)w0, 32);
        const unsigned int x1 = (unsigned int)__shfl_xor((int)w1, 32);
        const unsigned int x2 = (unsigned int)__shfl_xor((int)w2, 32);
        const unsigned int x3 = (unsigned int)__shfl_xor((int)w3, 32);
        u32x4 av;
        av[0] = hi ? x2 : w0;
        av[1] = hi ? x3 : w1;
        av[2] = hi ? w2 : x0;
        av[3] = hi ? w3 : x1;
        const short8 pf = __builtin_bit_cast(short8, av);
#pragma unroll
        for (int blk = 0; blk < 4; ++blk) {
          const int row2 = (blk & 1) * 32 + l31;
          const int cs = ((((blk >> 1) * 8) + ks * 2 + hi) ^ l15) * 8;
          const short8 vf = *(const short8*)&ldsV[row2 * 128 + cs];
          oacc[blk] = __builtin_amdgcn_mfma_f32_32x32x16_bf16(vf, pf, oacc[blk], 0, 0, 0);
        }
      }
      __builtin_amdgcn_s_setprio(0);
    }
  }

  // ---- epilogue: pair-reduce l, own-l normalize, store O partial + (m,l) ----
  const float l = l_run + __shfl_xor(l_run, 32);
  const float inv = (l > 0.f) ? (1.0f / l) : 0.f;
  unsigned short* yrow = (hf ? OB : OA) + ((size_t)(b * T + qrow)) * C + h * D;
#pragma unroll
  for (int blk = 0; blk < 4; ++blk)
#pragma unroll
    for (int g = 0; g < 4; ++g) {
      const int d0 = blk * 32 + 8 * g + 4 * hi;
      uint2 st;
      st.x = cvtpk(oacc[blk][4 * g + 0] * inv, oacc[blk][4 * g + 1] * inv);
      st.y = cvtpk(oacc[blk][4 * g + 2] * inv, oacc[blk][4 * g + 3] * inv);
      *(uint2*)&yrow[d0] = st;
    }
  if (hi == 0) {
    float2 v;
    v.x = m_run;
    v.y = l;
    ml[(size_t)hf * (Bdim * H * T) + (size_t)bh * T + qrow] = v;
  }
}

// ---------------- combine the two kv-half partials ----------------
__global__ __launch_bounds__(256) void combine_halves(const unsigned short* __restrict__ OA,
                                                      const unsigned short* __restrict__ OB,
                                                      const float2* __restrict__ ml,
                                                      unsigned short* __restrict__ Y) {
  const int i = blockIdx.x * 256 + threadIdx.x;  // [0, B*H*T*16)
  const int d0 = (i & 15) * 8;
  const int rowid = i >> 4;                      // bh*T + t
  const int bh = rowid >> 11, t = rowid & (T - 1);
  const int b = bh >> 4, h = bh & (H - 1);
  const float2 a = ml[rowid];
  const float2 bb = ml[(size_t)(Bdim * H * T) + rowid];
  const float m = fmaxf(a.x, bb.x);
  const float wA = a.y * exp2f(a.x - m);
  const float wB = bb.y * exp2f(bb.x - m);
  const float den = wA + wB;  // > 0: half A always has >=1 unmasked key
  const float fA = wA / den, fB = wB / den;
  const size_t off = ((size_t)(b * T + t)) * C + h * D + d0;
  const u32x4 ra = *(const u32x4*)&OA[off];
  const u32x4 rb = *(const u32x4*)&OB[off];
  u32x4 w;
#pragma unroll
  for (int e = 0; e < 4; ++e) {
    const float o0 = bf2f(ra[e] & 0xffffu) * fA + bf2f(rb[e] & 0xffffu) * fB;
    const float o1 = bf2f(ra[e] >> 16) * fA + bf2f(rb[e] >> 16) * fB;
    w[e] = cvtpk(o0, o1);
  }
  *(u32x4*)&Y[off] = w;
}

// ---------------- launch ----------------
extern "C" void kernel_launch(void* const* d_in, const int* in_sizes, int n_in,
                              void* d_out, int out_size, void* d_ws, size_t ws_size,
                              hipStream_t stream) {
  const float* x = (const float*)d_in[0];
  const float* wqkv = (const float*)d_in[1];
  const float* wo = (const float*)d_in[2];
  const float* rc = (const float*)d_in[3];
  const float* rs = (const float*)d_in[4];
  float* out = (float*)d_out;
  char* ws = (char*)d_ws;

  unsigned short* xb    = (unsigned short*)(ws + 0);           // 16.8 MB
  unsigned short* wqkvb = (unsigned short*)(ws + 16777216);    // 25.2 MB
  unsigned short* qkv   = (unsigned short*)(ws + 41943040);    // 50.3 MB
  unsigned short* Qr    = (unsigned short*)(ws + 92274688);    // 16.8 MB
  unsigned short* Kr    = (unsigned short*)(ws + 109051904);   // 16.8 MB
  unsigned short* wob   = (unsigned short*)(ws + 125829120);   // 8.4 MB
  unsigned short* Vt  = xb;    // alias: xb dead after GEMM1
  // flash-phase aliases inside the (then-dead) qkv slot:
  unsigned short* OA  = (unsigned short*)(ws + 41943040);      // 16.8 MB
  unsigned short* OB  = (unsigned short*)(ws + 58720256);      // 16.8 MB
  float2*         ml  = (float2*)(ws + 75497472);              // 1.0 MB
  unsigned short* Yf  = Qr;    // alias: Qr dead after flash

  convert_all<<<8192 + 12288 + 4096, 256, 0, stream>>>(x, wqkv, wo, xb, wqkvb, wob);
  gemm_bt<1><<<dim3(CQ / 128, (Bdim * T) / 128), 256, 0, stream>>>(xb, wqkvb, (void*)qkv,
                                                                   Bdim * T, CQ, C);
  rope_vt_kernel<<<18432, 256, 0, stream>>>(qkv, rc, rs, Qr, Kr, Vt);
  flash_attn<<<1024, 256, 0, stream>>>(Qr, Kr, Vt, OA, OB, ml);
  combine_halves<<<4096, 256, 0, stream>>>(OA, OB, ml, Yf);
  gemm_bt<0><<<dim3(C / 128, (Bdim * T) / 128), 256, 0, stream>>>(Yf, wob, (void*)out,
                                                                  Bdim * T, C, C);
}